// Round 6
// baseline (396.691 us; speedup 1.0000x reference)
//
#include <hip/hip_runtime.h>
#include <math.h>

#define B_ 32
#define S_ 1024
#define H_ 512
#define K_ 1024                 // 2*H
#define M_ (B_ * S_)            // 32768

typedef __attribute__((ext_vector_type(8))) short bf16x8;
typedef __attribute__((ext_vector_type(4))) float f32x4;

// RNE split (used for B prep): f = hi + lo, dropped cross-term ~2^-18
__device__ __forceinline__ void split_bf16(float f, unsigned short& hi, unsigned short& lo) {
    unsigned u = __float_as_uint(f);
    unsigned rh = (u + 0x7fffu + ((u >> 16) & 1u)) >> 16;
    hi = (unsigned short)rh;
    float fh = __uint_as_float(rh << 16);
    float r = f - fh;
    unsigned ur = __float_as_uint(r);
    unsigned rl = (ur + 0x7fffu + ((ur >> 16) & 1u)) >> 16;
    lo = (unsigned short)rl;
}

// cheap truncation split for A (in-register, ~4-5 VALU/elem):
//   hi = top 16 bits of f (trunc);  r = f - hi  (EXACT, Sterbenz);
//   lo = top 16 bits of r (trunc, err <= 2^-16 |f| -> negligible)
__device__ __forceinline__ void cheap_split8(const float4& x, const float4& y,
                                             bf16x8& h, bf16x8& l) {
    union { unsigned short us[8]; bf16x8 v; } H, L;
    const float f[8] = {x.x, x.y, x.z, x.w, y.x, y.y, y.z, y.w};
    #pragma unroll
    for (int j = 0; j < 8; ++j) {
        const unsigned u = __float_as_uint(f[j]);
        H.us[j] = (unsigned short)(u >> 16);
        const float r = f[j] - __uint_as_float(u & 0xffff0000u);
        L.us[j] = (unsigned short)(__float_as_uint(r) >> 16);
    }
    h = H.v;
    l = L.v;
}

// async 16B global -> LDS (lane i lands at lds_base + i*16)
__device__ __forceinline__ void async_copy16(const void* g, void* l) {
    __builtin_amdgcn_global_load_lds(
        (const __attribute__((address_space(1))) void*)g,
        (__attribute__((address_space(3))) void*)l, 16, 0, 0);
}

// ---------------------------------------------------------------------------
// Kernel 1: hb[b][h] = sum_k hidden[b][k]*W[k][h] + bias[h]
// ---------------------------------------------------------------------------
__global__ __launch_bounds__(256) void hproj_kernel(
    const float* __restrict__ hidden, const float* __restrict__ W,
    const float* __restrict__ bias, float* __restrict__ hb)
{
    const int tid = threadIdx.x;
    const int h0  = blockIdx.x * 64;
    const int b   = blockIdx.y;
    const int h   = h0 + (tid & 63);
    const int ks  = tid >> 6;              // 4 k-slices of 128
    const float* hrow = hidden + b * H_;
    float acc = 0.f;
    #pragma unroll 8
    for (int k = ks * 128; k < ks * 128 + 128; ++k)
        acc = fmaf(hrow[k], W[(size_t)k * H_ + h], acc);
    __shared__ float red[4][64];
    red[ks][tid & 63] = acc;
    __syncthreads();
    if (tid < 64)
        hb[b * H_ + h0 + tid] = red[0][tid] + red[1][tid] + red[2][tid]
                              + red[3][tid] + bias[h0 + tid];
}

// ---------------------------------------------------------------------------
// Kernel 1b: transpose + RNE bf16-split We (K x 512) -> Wth/Wtl (512 x K)
// ---------------------------------------------------------------------------
__global__ __launch_bounds__(256) void conv_we_kernel(
    const float* __restrict__ We, unsigned short* __restrict__ Wh,
    unsigned short* __restrict__ Wl)
{
    __shared__ float t[32][33];
    const int tx = threadIdx.x & 31, ty = threadIdx.x >> 5;   // ty 0..7
    const int k0 = blockIdx.x * 32, n0 = blockIdx.y * 32;
    #pragma unroll
    for (int j = 0; j < 4; ++j) {
        const int k = ty + 8 * j;
        t[k][tx] = We[(size_t)(k0 + k) * H_ + n0 + tx];
    }
    __syncthreads();
    #pragma unroll
    for (int j = 0; j < 4; ++j) {
        const int n = ty + 8 * j;
        unsigned short hi, lo;
        split_bf16(t[tx][n], hi, lo);
        Wh[(size_t)(n0 + n) * K_ + k0 + tx] = hi;
        Wl[(size_t)(n0 + n) * K_ + k0 + tx] = lo;
    }
}

// ---------------------------------------------------------------------------
// Kernel 2: MFMA GEMM. A: fp32 global -> regs -> trunc-split -> MFMA directly
// (no A LDS, no split tail). B: pre-split bf16 via global_load_lds dbuf DMA,
// XOR-quarter swizzle (0 conflicts, verified r3/r4). LDS = B only, 32 KB.
// XCD swizzle: 4 nt-blocks of one mt share one XCD -> A re-reads are L2 hits.
// Block 128x128, BK=32, 4 waves 2x2 of 64x64, 16x16x32 bf16 MFMA x3.
// ---------------------------------------------------------------------------
__global__ __launch_bounds__(256, 3) void gemm_fused(
    const float* __restrict__ EO,             // (M, K) fp32
    const unsigned short* __restrict__ Bth,   // (512, K) bf16 hi
    const unsigned short* __restrict__ Btl,   // (512, K) bf16 lo
    const float* __restrict__ hb, const float* __restrict__ v,
    float* __restrict__ partial)              // (4, M)
{
    __shared__ unsigned short ldsB[2][2][4096];   // [buf][hi|lo][128*32] = 32 KB

    const int tid = threadIdx.x;
    const int bid = blockIdx.x;               // 0..1023
    // XCD co-location: ids {k, k+8, k+16, k+24} are the 4 nt of one mt and
    // land on the same XCD under round-robin dispatch.
    const int mt = (bid & 7) + ((bid >> 5) << 3);   // 0..255
    const int nt = (bid >> 3) & 3;                  // 0..3
    const int row0 = mt * 128;
    const int col0 = nt * 128;
    const int batch = row0 >> 10;

    const int lane   = tid & 63;
    const int wave   = tid >> 6;
    const int wm     = wave >> 1, wn = wave & 1;
    const int lanelo = lane & 15, quad = lane >> 4;

    // ---- B staging geometry (DMA): issue = 16 rows x 64B; wave w: 2w,2w+1 ----
    size_t gb[2];
    int offB[2];
    #pragma unroll
    for (int j = 0; j < 2; ++j) {
        const int iss = wave * 2 + j;
        const int r   = iss * 16 + (lane >> 2);
        const int qg  = (lane & 3) ^ ((r >> 1) & 3);
        gb[j] = (size_t)(col0 + r) * K_ + qg * 8;
        offB[j] = iss * 512;                  // shorts
    }

    // ---- A fragment pointer: lane reads 8 consecutive fp32 per fi ----
    const float* aptr = EO + (size_t)(row0 + wm * 64 + lanelo) * K_ + quad * 8;
    // fi stride in elements:
    const int AFI = 16 * K_;

    f32x4 acc[4][4];
    #pragma unroll
    for (int i = 0; i < 4; ++i)
        #pragma unroll
        for (int j = 0; j < 4; ++j)
            acc[i][j] = (f32x4){0.f, 0.f, 0.f, 0.f};

    // ---- prologue: B DMA tile 0, A regs tile 0 ----
    #pragma unroll
    for (int j = 0; j < 2; ++j) {
        async_copy16(Bth + gb[j], &ldsB[0][0][offB[j]]);
        async_copy16(Btl + gb[j], &ldsB[0][1][offB[j]]);
    }
    float4 af0[4], af1[4];
    #pragma unroll
    for (int fi = 0; fi < 4; ++fi) {
        af0[fi] = *reinterpret_cast<const float4*>(aptr + fi * AFI);
        af1[fi] = *reinterpret_cast<const float4*>(aptr + fi * AFI + 4);
    }

    for (int i = 0; i < 32; ++i) {
        __syncthreads();                      // drains B DMA into buf[cur]
        const int cur = i & 1, nxt = cur ^ 1;
        const int k0n = 32 * (i + 1);
        if (i < 31) {
            #pragma unroll
            for (int j = 0; j < 2; ++j) {
                async_copy16(Bth + gb[j] + k0n, &ldsB[nxt][0][offB[j]]);
                async_copy16(Btl + gb[j] + k0n, &ldsB[nxt][1][offB[j]]);
            }
        }

        // B fragments from LDS (conflict-free XOR-quarter layout)
        bf16x8 b_h[4], b_l[4];
        #pragma unroll
        for (int fj = 0; fj < 4; ++fj) {
            const int n  = wn * 64 + fj * 16 + lanelo;
            const int sb = quad ^ ((n >> 1) & 3);
            b_h[fj] = *reinterpret_cast<const bf16x8*>(&ldsB[cur][0][n * 32 + sb * 8]);
            b_l[fj] = *reinterpret_cast<const bf16x8*>(&ldsB[cur][1][n * 32 + sb * 8]);
        }

        // fi-granular: split A(i), reload A(i+1) into freed regs, 12 MFMAs
        #pragma unroll
        for (int fi = 0; fi < 4; ++fi) {
            bf16x8 ah, al;
            cheap_split8(af0[fi], af1[fi], ah, al);
            if (i < 31) {
                af0[fi] = *reinterpret_cast<const float4*>(aptr + fi * AFI + k0n);
                af1[fi] = *reinterpret_cast<const float4*>(aptr + fi * AFI + k0n + 4);
            }
            #pragma unroll
            for (int fj = 0; fj < 4; ++fj) {
                acc[fi][fj] = __builtin_amdgcn_mfma_f32_16x16x32_bf16(
                    ah, b_h[fj], acc[fi][fj], 0, 0, 0);
                acc[fi][fj] = __builtin_amdgcn_mfma_f32_16x16x32_bf16(
                    ah, b_l[fj], acc[fi][fj], 0, 0, 0);
                acc[fi][fj] = __builtin_amdgcn_mfma_f32_16x16x32_bf16(
                    al, b_h[fj], acc[fi][fj], 0, 0, 0);
            }
        }
    }

    // ---- epilogue: tanh(acc + hb)*v, reduce over this block's 128 cols ----
    // Last iter read ldsB[1]; red uses ldsB[0] region (disjoint) -> no hazard.
    const float* hb_row = hb + batch * H_;
    float hbv[4], vv[4];
    #pragma unroll
    for (int fj = 0; fj < 4; ++fj) {
        const int c = col0 + wn * 64 + fj * 16 + lanelo;
        hbv[fj] = hb_row[c];
        vv[fj]  = v[c];
    }
    float* red = reinterpret_cast<float*>(&ldsB[0][0][0]);   // 256 floats
    #pragma unroll
    for (int fi = 0; fi < 4; ++fi)
        #pragma unroll
        for (int r = 0; r < 4; ++r) {
            float rs = 0.f;
            #pragma unroll
            for (int fj = 0; fj < 4; ++fj)
                rs = fmaf(tanhf(acc[fi][fj][r] + hbv[fj]), vv[fj], rs);
            rs += __shfl_xor(rs, 1, 64);
            rs += __shfl_xor(rs, 2, 64);
            rs += __shfl_xor(rs, 4, 64);
            rs += __shfl_xor(rs, 8, 64);
            if (lanelo == 0) {
                const int row = wm * 64 + fi * 16 + quad * 4 + r;
                red[row * 2 + wn] = rs;
            }
        }
    __syncthreads();
    if (tid < 128)
        partial[(size_t)nt * M_ + row0 + tid] = red[tid * 2] + red[tid * 2 + 1];
}

// ---------------------------------------------------------------------------
// Kernel 3: per-batch softmax over S=1024 (sum of 4 partials)
// ---------------------------------------------------------------------------
__global__ __launch_bounds__(256) void softmax_kernel(
    const float* __restrict__ partial, float* __restrict__ out)
{
    const int b = blockIdx.x;
    const int tid = threadIdx.x;
    float val[4];
    float lmax = -3.0e38f;
    #pragma unroll
    for (int q = 0; q < 4; ++q) {
        const int idx = b * S_ + tid + 256 * q;
        float sum = partial[idx] + partial[M_ + idx] + partial[2 * M_ + idx] +
                    partial[3 * M_ + idx];
        val[q] = sum;
        lmax = fmaxf(lmax, sum);
    }
    #pragma unroll
    for (int off = 32; off > 0; off >>= 1)
        lmax = fmaxf(lmax, __shfl_down(lmax, off, 64));
    __shared__ float wmax[4];
    if ((tid & 63) == 0) wmax[tid >> 6] = lmax;
    __syncthreads();
    const float gmax = fmaxf(fmaxf(wmax[0], wmax[1]), fmaxf(wmax[2], wmax[3]));
    float lsum = 0.0f;
    #pragma unroll
    for (int q = 0; q < 4; ++q) {
        val[q] = expf(val[q] - gmax);
        lsum += val[q];
    }
    #pragma unroll
    for (int off = 32; off > 0; off >>= 1)
        lsum += __shfl_down(lsum, off, 64);
    __shared__ float wsum[4];
    if ((tid & 63) == 0) wsum[tid >> 6] = lsum;
    __syncthreads();
    const float inv = 1.0f / (wsum[0] + wsum[1] + wsum[2] + wsum[3]);
    #pragma unroll
    for (int q = 0; q < 4; ++q)
        out[b * S_ + tid + 256 * q] = val[q] * inv;
}

// ---------------------------------------------------------------------------
extern "C" void kernel_launch(void* const* d_in, const int* in_sizes, int n_in,
                              void* d_out, int out_size, void* d_ws, size_t ws_size,
                              hipStream_t stream) {
    const float* hidden = (const float*)d_in[0];
    const float* EO     = (const float*)d_in[1];
    const float* W      = (const float*)d_in[2];
    const float* bias   = (const float*)d_in[3];
    const float* v      = (const float*)d_in[4];
    float* out          = (float*)d_out;

    float* hb      = (float*)d_ws;                       // 16384 floats
    float* partial = hb + B_ * H_;                       // 131072 floats
    unsigned short* Wth = (unsigned short*)(partial + 4 * M_);
    unsigned short* Wtl = Wth + (size_t)H_ * K_;

    const float* We = W + (size_t)H_ * H_;               // rows [H, 3H)

    hproj_kernel<<<dim3(8, B_), 256, 0, stream>>>(hidden, W, bias, hb);
    conv_we_kernel<<<dim3(K_ / 32, H_ / 32), 256, 0, stream>>>(We, Wth, Wtl);
    gemm_fused<<<1024, 256, 0, stream>>>(EO, Wth, Wtl, hb, v, partial);
    softmax_kernel<<<B_, 256, 0, stream>>>(partial, out);
}

// Round 7
// 322.538 us; speedup vs baseline: 1.2299x; 1.2299x over previous
//
#include <hip/hip_runtime.h>
#include <math.h>

#define B_ 32
#define S_ 1024
#define H_ 512
#define K_ 1024                 // 2*H
#define M_ (B_ * S_)            // 32768

typedef __attribute__((ext_vector_type(8))) short bf16x8;
typedef __attribute__((ext_vector_type(4))) float f32x4;

// RNE split (B prep): f = hi + lo, dropped cross-term ~2^-19
__device__ __forceinline__ void split_bf16(float f, unsigned short& hi, unsigned short& lo) {
    unsigned u = __float_as_uint(f);
    unsigned rh = (u + 0x7fffu + ((u >> 16) & 1u)) >> 16;
    hi = (unsigned short)rh;
    float fh = __uint_as_float(rh << 16);
    float r = f - fh;
    unsigned ur = __float_as_uint(r);
    unsigned rl = (ur + 0x7fffu + ((ur >> 16) & 1u)) >> 16;
    lo = (unsigned short)rl;
}

// cheap truncation split for A (in-register):
//   hi = top16(f) (trunc);  r = f - hi (EXACT: same exponent, aligned sub);
//   lo = top16(r) (trunc, residual <= 2^-16 |f|). Proven numerics (r6 passed
//   with identical split: absmax 1.5e-5 vs threshold 1.3e-4).
__device__ __forceinline__ void cheap_split8(const float4& x, const float4& y,
                                             bf16x8& h, bf16x8& l) {
    union { unsigned short us[8]; bf16x8 v; } H, L;
    const float f[8] = {x.x, x.y, x.z, x.w, y.x, y.y, y.z, y.w};
    #pragma unroll
    for (int j = 0; j < 8; ++j) {
        const unsigned u = __float_as_uint(f[j]);
        H.us[j] = (unsigned short)(u >> 16);
        const float r = f[j] - __uint_as_float(u & 0xffff0000u);
        L.us[j] = (unsigned short)(__float_as_uint(r) >> 16);
    }
    h = H.v;
    l = L.v;
}

// async 16B global -> LDS (lane i lands at lds_base + i*16)
__device__ __forceinline__ void async_copy16(const void* g, void* l) {
    __builtin_amdgcn_global_load_lds(
        (const __attribute__((address_space(1))) void*)g,
        (__attribute__((address_space(3))) void*)l, 16, 0, 0);
}

// ---------------------------------------------------------------------------
// Kernel 1: hb[b][h] = sum_k hidden[b][k]*W[k][h] + bias[h]
// ---------------------------------------------------------------------------
__global__ __launch_bounds__(256) void hproj_kernel(
    const float* __restrict__ hidden, const float* __restrict__ W,
    const float* __restrict__ bias, float* __restrict__ hb)
{
    const int tid = threadIdx.x;
    const int h0  = blockIdx.x * 64;
    const int b   = blockIdx.y;
    const int h   = h0 + (tid & 63);
    const int ks  = tid >> 6;              // 4 k-slices of 128
    const float* hrow = hidden + b * H_;
    float acc = 0.f;
    #pragma unroll 8
    for (int k = ks * 128; k < ks * 128 + 128; ++k)
        acc = fmaf(hrow[k], W[(size_t)k * H_ + h], acc);
    __shared__ float red[4][64];
    red[ks][tid & 63] = acc;
    __syncthreads();
    if (tid < 64)
        hb[b * H_ + h0 + tid] = red[0][tid] + red[1][tid] + red[2][tid]
                              + red[3][tid] + bias[h0 + tid];
}

// ---------------------------------------------------------------------------
// Kernel 1b: transpose + RNE bf16-split We (K x 512) -> Wth/Wtl (512 x K)
// ---------------------------------------------------------------------------
__global__ __launch_bounds__(256) void conv_we_kernel(
    const float* __restrict__ We, unsigned short* __restrict__ Wh,
    unsigned short* __restrict__ Wl)
{
    __shared__ float t[32][33];
    const int tx = threadIdx.x & 31, ty = threadIdx.x >> 5;   // ty 0..7
    const int k0 = blockIdx.x * 32, n0 = blockIdx.y * 32;
    #pragma unroll
    for (int j = 0; j < 4; ++j) {
        const int k = ty + 8 * j;
        t[k][tx] = We[(size_t)(k0 + k) * H_ + n0 + tx];
    }
    __syncthreads();
    #pragma unroll
    for (int j = 0; j < 4; ++j) {
        const int n = ty + 8 * j;
        unsigned short hi, lo;
        split_bf16(t[tx][n], hi, lo);
        Wh[(size_t)(n0 + n) * K_ + k0 + tx] = hi;
        Wl[(size_t)(n0 + n) * K_ + k0 + tx] = lo;
    }
}

// ---------------------------------------------------------------------------
// Kernel 2: MFMA GEMM. A: raw fp32 DMA'd to LDS (same bytes as hi+lo!),
// split in-register AFTER the frag ds_read (pipelined across fi, co-issues
// with MFMA). B: pre-split bf16 DMA. Double-buffered, 1 barrier/iter (r4
// structure, its best-measured regime). XCD swizzle: 4 nt-blocks of one mt
// co-located -> A re-reads hit L2 (r6: FETCH 267->86 MB).
// A-LDS: 128B rows => banks depend only on 16B-unit index; store phys unit
// p = logical ^ (row&7) (XOR on global side during DMA) => frag reads 2-way.
// Block 128x128, BK=32, 4 waves 2x2 of 64x64, 16x16x32 bf16 MFMA x3.
// ---------------------------------------------------------------------------
__global__ __launch_bounds__(256, 2) void gemm_fused(
    const float* __restrict__ EO,             // (M, K) fp32
    const unsigned short* __restrict__ Bth,   // (512, K) bf16 hi
    const unsigned short* __restrict__ Btl,   // (512, K) bf16 lo
    const float* __restrict__ hb, const float* __restrict__ v,
    float* __restrict__ partial)              // (4, M)
{
    __shared__ float          ldsA[2][4096];      // [buf][128 rows x 32 f32] 16KB
    __shared__ unsigned short ldsB[2][2][4096];   // [buf][hi|lo][128 x 32]  8KB

    const int tid = threadIdx.x;
    const int bid = blockIdx.x;               // 0..1023
    // XCD co-location: {k, k+8, k+16, k+24} = the 4 nt of one mt, same XCD.
    const int mt = (bid & 7) + ((bid >> 5) << 3);   // 0..255
    const int nt = (bid >> 3) & 3;                  // 0..3
    const int row0 = mt * 128;
    const int col0 = nt * 128;
    const int batch = row0 >> 10;

    const int lane   = tid & 63;
    const int wave   = tid >> 6;
    const int wm     = wave >> 1, wn = wave & 1;
    const int lanelo = lane & 15, quad = lane >> 4;

    // ---- B staging (DMA): issue = 16 rows x 64B; wave w: issues 2w,2w+1 ----
    size_t gb[2];
    int offB[2];
    #pragma unroll
    for (int j = 0; j < 2; ++j) {
        const int iss = wave * 2 + j;
        const int r   = iss * 16 + (lane >> 2);
        const int qg  = (lane & 3) ^ ((r >> 1) & 3);
        gb[j] = (size_t)(col0 + r) * K_ + qg * 8;
        offB[j] = iss * 512;                  // shorts
    }
    // ---- A staging (DMA): issue = 8 rows x 128B; wave w: issues 4w..4w+3 ----
    size_t gaA[4];
    int offA[4];
    #pragma unroll
    for (int j = 0; j < 4; ++j) {
        const int iss = wave * 4 + j;
        const int r   = iss * 8 + (lane >> 3);      // tile row
        const int up  = lane & 7;                   // physical 16B unit
        const int ul  = up ^ (r & 7);               // logical 16B unit
        gaA[j] = (size_t)(row0 + r) * K_ + ul * 4;  // float offset
        offA[j] = iss * 256;                        // floats (1KB per issue)
    }

    f32x4 acc[4][4];
    #pragma unroll
    for (int i = 0; i < 4; ++i)
        #pragma unroll
        for (int j = 0; j < 4; ++j)
            acc[i][j] = (f32x4){0.f, 0.f, 0.f, 0.f};

    // ---- prologue: stage tile 0 into buf 0 ----
    #pragma unroll
    for (int j = 0; j < 4; ++j)
        async_copy16(EO + gaA[j], &ldsA[0][offA[j]]);
    #pragma unroll
    for (int j = 0; j < 2; ++j) {
        async_copy16(Bth + gb[j], &ldsB[0][0][offB[j]]);
        async_copy16(Btl + gb[j], &ldsB[0][1][offB[j]]);
    }

    for (int i = 0; i < 32; ++i) {
        __syncthreads();                      // drains DMA into buf[cur]
        const int cur = i & 1, nxt = cur ^ 1;
        const int k0n = 32 * (i + 1);
        if (i < 31) {                         // prefetch tile i+1 (full body in flight)
            #pragma unroll
            for (int j = 0; j < 4; ++j)
                async_copy16(EO + gaA[j] + k0n, &ldsA[nxt][offA[j]]);
            #pragma unroll
            for (int j = 0; j < 2; ++j) {
                async_copy16(Bth + gb[j] + k0n, &ldsB[nxt][0][offB[j]]);
                async_copy16(Btl + gb[j] + k0n, &ldsB[nxt][1][offB[j]]);
            }
        }

        // B fragments from LDS (XOR-quarter layout; 0 conflicts, r3/r4)
        bf16x8 b_h[4], b_l[4];
        #pragma unroll
        for (int fj = 0; fj < 4; ++fj) {
            const int n  = wn * 64 + fj * 16 + lanelo;
            const int sb = quad ^ ((n >> 1) & 3);
            b_h[fj] = *reinterpret_cast<const bf16x8*>(&ldsB[cur][0][n * 32 + sb * 8]);
            b_l[fj] = *reinterpret_cast<const bf16x8*>(&ldsB[cur][1][n * 32 + sb * 8]);
        }

        // A: fp32 frag read (two b128, 2-way banks) -> reg split -> 12 MFMAs
        #pragma unroll
        for (int fi = 0; fi < 4; ++fi) {
            const int m  = wm * 64 + fi * 16 + lanelo;
            const int mb = m * 32;
            const int u0 = (((quad << 1) | 0) ^ (m & 7)) << 2;  // float offs
            const int u1 = (((quad << 1) | 1) ^ (m & 7)) << 2;
            const float4 x = *reinterpret_cast<const float4*>(&ldsA[cur][mb + u0]);
            const float4 y = *reinterpret_cast<const float4*>(&ldsA[cur][mb + u1]);
            bf16x8 ah, al;
            cheap_split8(x, y, ah, al);
            #pragma unroll
            for (int fj = 0; fj < 4; ++fj) {
                acc[fi][fj] = __builtin_amdgcn_mfma_f32_16x16x32_bf16(
                    ah, b_h[fj], acc[fi][fj], 0, 0, 0);
                acc[fi][fj] = __builtin_amdgcn_mfma_f32_16x16x32_bf16(
                    ah, b_l[fj], acc[fi][fj], 0, 0, 0);
                acc[fi][fj] = __builtin_amdgcn_mfma_f32_16x16x32_bf16(
                    al, b_h[fj], acc[fi][fj], 0, 0, 0);
            }
        }
    }

    // ---- epilogue: tanh(acc + hb)*v, reduce over this block's 128 cols ----
    // i=31 read buf 1; red reuses ldsA[0] (last touched i<=30, pre-barrier).
    const float* hb_row = hb + batch * H_;
    float hbv[4], vv[4];
    #pragma unroll
    for (int fj = 0; fj < 4; ++fj) {
        const int c = col0 + wn * 64 + fj * 16 + lanelo;
        hbv[fj] = hb_row[c];
        vv[fj]  = v[c];
    }
    float* red = &ldsA[0][0];                 // 256 floats
    #pragma unroll
    for (int fi = 0; fi < 4; ++fi)
        #pragma unroll
        for (int r = 0; r < 4; ++r) {
            float rs = 0.f;
            #pragma unroll
            for (int fj = 0; fj < 4; ++fj)
                rs = fmaf(tanhf(acc[fi][fj][r] + hbv[fj]), vv[fj], rs);
            rs += __shfl_xor(rs, 1, 64);
            rs += __shfl_xor(rs, 2, 64);
            rs += __shfl_xor(rs, 4, 64);
            rs += __shfl_xor(rs, 8, 64);
            if (lanelo == 0) {
                const int row = wm * 64 + fi * 16 + quad * 4 + r;
                red[row * 2 + wn] = rs;
            }
        }
    __syncthreads();
    if (tid < 128)
        partial[(size_t)nt * M_ + row0 + tid] = red[tid * 2] + red[tid * 2 + 1];
}

// ---------------------------------------------------------------------------
// Kernel 3: per-batch softmax over S=1024 (sum of 4 partials)
// ---------------------------------------------------------------------------
__global__ __launch_bounds__(256) void softmax_kernel(
    const float* __restrict__ partial, float* __restrict__ out)
{
    const int b = blockIdx.x;
    const int tid = threadIdx.x;
    float val[4];
    float lmax = -3.0e38f;
    #pragma unroll
    for (int q = 0; q < 4; ++q) {
        const int idx = b * S_ + tid + 256 * q;
        float sum = partial[idx] + partial[M_ + idx] + partial[2 * M_ + idx] +
                    partial[3 * M_ + idx];
        val[q] = sum;
        lmax = fmaxf(lmax, sum);
    }
    #pragma unroll
    for (int off = 32; off > 0; off >>= 1)
        lmax = fmaxf(lmax, __shfl_down(lmax, off, 64));
    __shared__ float wmax[4];
    if ((tid & 63) == 0) wmax[tid >> 6] = lmax;
    __syncthreads();
    const float gmax = fmaxf(fmaxf(wmax[0], wmax[1]), fmaxf(wmax[2], wmax[3]));
    float lsum = 0.0f;
    #pragma unroll
    for (int q = 0; q < 4; ++q) {
        val[q] = expf(val[q] - gmax);
        lsum += val[q];
    }
    #pragma unroll
    for (int off = 32; off > 0; off >>= 1)
        lsum += __shfl_down(lsum, off, 64);
    __shared__ float wsum[4];
    if ((tid & 63) == 0) wsum[tid >> 6] = lsum;
    __syncthreads();
    const float inv = 1.0f / (wsum[0] + wsum[1] + wsum[2] + wsum[3]);
    #pragma unroll
    for (int q = 0; q < 4; ++q)
        out[b * S_ + tid + 256 * q] = val[q] * inv;
}

// ---------------------------------------------------------------------------
extern "C" void kernel_launch(void* const* d_in, const int* in_sizes, int n_in,
                              void* d_out, int out_size, void* d_ws, size_t ws_size,
                              hipStream_t stream) {
    const float* hidden = (const float*)d_in[0];
    const float* EO     = (const float*)d_in[1];
    const float* W      = (const float*)d_in[2];
    const float* bias   = (const float*)d_in[3];
    const float* v      = (const float*)d_in[4];
    float* out          = (float*)d_out;

    float* hb      = (float*)d_ws;                       // 16384 floats
    float* partial = hb + B_ * H_;                       // 131072 floats
    unsigned short* Wth = (unsigned short*)(partial + 4 * M_);
    unsigned short* Wtl = Wth + (size_t)H_ * K_;

    const float* We = W + (size_t)H_ * H_;               // rows [H, 3H)

    hproj_kernel<<<dim3(8, B_), 256, 0, stream>>>(hidden, W, bias, hb);
    conv_we_kernel<<<dim3(K_ / 32, H_ / 32), 256, 0, stream>>>(We, Wth, Wtl);
    gemm_fused<<<1024, 256, 0, stream>>>(EO, Wth, Wtl, hb, v, partial);
    softmax_kernel<<<B_, 256, 0, stream>>>(partial, out);
}